// Round 13
// baseline (181.505 us; speedup 1.0000x reference)
//
#include <hip/hip_runtime.h>

typedef _Float16 f16x8 __attribute__((ext_vector_type(8)));
typedef _Float16 f16x4 __attribute__((ext_vector_type(4)));
typedef float f32x4 __attribute__((ext_vector_type(4)));

#define MFMA32(A, B, C) __builtin_amdgcn_mfma_f32_16x16x32_f16(A, B, C, 0, 0, 0)
#define MFMA16(A, B, C) __builtin_amdgcn_mfma_f32_16x16x16f16(A, B, C, 0, 0, 0)

struct P16 { f16x8 hi, lo; };
struct P8  { f16x4 hi, lo; };

__device__ __forceinline__ P16 split16(float4 a, float4 b) {
  float v[8] = {a.x, a.y, a.z, a.w, b.x, b.y, b.z, b.w};
  P16 p;
#pragma unroll
  for (int e = 0; e < 8; ++e) {
    const _Float16 h = (_Float16)v[e];
    p.hi[e] = h; p.lo[e] = (_Float16)(v[e] - (float)h);
  }
  return p;
}
__device__ __forceinline__ P8 split4(float a0, float a1, float a2, float a3) {
  float v[4] = {a0, a1, a2, a3};
  P8 p;
#pragma unroll
  for (int e = 0; e < 4; ++e) {
    const _Float16 h = (_Float16)v[e];
    p.hi[e] = h; p.lo[e] = (_Float16)(v[e] - (float)h);
  }
  return p;
}
__device__ __forceinline__ float sigm(float a) {
  return __builtin_amdgcn_rcpf(1.0f + __expf(-a));
}

// W [512][28] f32 -> f16 hi/lo fragment planes: wf[{0,1}*32 + T][lane] = uint4
// element e: k = 4g+e (e<4) | 16+4g+(e-4), g=lane>>4; W-col = 16T + (lane&15)
__global__ void prep_wfrag(const float* __restrict__ W, uint4* __restrict__ wf) {
  const int id = blockIdx.x * 256 + threadIdx.x;
  if (id >= 2048) return;
  const int T = id >> 6, l = id & 63, g = (l >> 4) & 3, li = l & 15;
  const int col = 16 * T + li;
  unsigned hi[8], lo[8];
#pragma unroll
  for (int e = 0; e < 8; ++e) {
    const int k = (e < 4) ? (4 * g + e) : (16 + 4 * g + (e - 4));
    const float v = (k < 28) ? W[col * 28 + k] : 0.0f;
    const _Float16 h = (_Float16)v;
    const _Float16 lw = (_Float16)(v - (float)h);
    hi[e] = __builtin_bit_cast(unsigned short, h);
    lo[e] = __builtin_bit_cast(unsigned short, lw);
  }
  uint4 uh, ul;
  uh.x = hi[0] | (hi[1] << 16); uh.y = hi[2] | (hi[3] << 16);
  uh.z = hi[4] | (hi[5] << 16); uh.w = hi[6] | (hi[7] << 16);
  ul.x = lo[0] | (lo[1] << 16); ul.y = lo[2] | (lo[3] << 16);
  ul.z = lo[4] | (lo[5] << 16); ul.w = lo[6] | (lo[7] << 16);
  wf[T * 64 + l] = uh;
  wf[(32 + T) * 64 + l] = ul;
}

// TWO WAVES = ONE SAMPLE; 128-thread blocks; exactly ONE __syncthreads.
// Wave w handles H/B tiles 16w..16w+15. G partials exchanged via LDS park:
//   per-wave region (1792 words): [0,512) transpose buf (G phase)
//                                 [0,896)  Gc (post-barrier; transpose dead)
//                                 [0,1024) Yt (post-solve; Gc dead)
//                                 [1024,1792) parked G partials (stable after
//                                             park; partner reads post-barrier;
//                                             own post-barrier writes all <1024)
// Solve duplicated per wave (cheaper than a second sync). X = x (full row-rank).
// B = H^T Y with H recomputed per tile (C-frag == B-operand frag), direct stores.
__global__ __launch_bounds__(128, 6) void elm_kernel(
    const float* __restrict__ x, const uint4* __restrict__ wf,
    const float* __restrict__ bias, float* __restrict__ Xout,
    float* __restrict__ Bout)
{
  __shared__ __align__(16) float sm[3584];   // 14336 B: 2 x 1792-word wave regions
  const int tid = threadIdx.x, n = blockIdx.x;
  const int w = tid >> 6, l = tid & 63, gl = l >> 4, li = l & 15;
  const int wb = w * 1792, pb = (w ^ 1) * 1792;
  const float* xi = x + (size_t)n * 784;

  // ---- 1. X = x (both waves share the copy) ----
  {
    const float4* x4 = reinterpret_cast<const float4*>(xi);
    float4* X4 = reinterpret_cast<float4*>(Xout + (size_t)n * 784);
#pragma unroll
    for (int k = 0; k < 2; ++k) {
      const int idx = tid + 128 * k;
      if (idx < 196) X4[idx] = x4[idx];
    }
  }

  // ---- 2. x A-fragments direct from global (row stride 112B, 16B-aligned) ----
  const float4 z4 = {0, 0, 0, 0};
  const float4 xa0 = *reinterpret_cast<const float4*>(xi + li * 28 + 4 * gl);
  const float4 xb0 = (gl < 3) ? *reinterpret_cast<const float4*>(xi + li * 28 + 16 + 4 * gl) : z4;
  const int r1 = (li < 12) ? 16 + li : 0;
  float4 xa1 = *reinterpret_cast<const float4*>(xi + r1 * 28 + 4 * gl);
  float4 xb1 = (gl < 3) ? *reinterpret_cast<const float4*>(xi + r1 * 28 + 16 + 4 * gl) : z4;
  if (li >= 12) { xa1 = z4; xb1 = z4; }
  const P16 X0 = split16(xa0, xb0);
  const P16 X1 = split16(xa1, xb1);

  // ---- 3. H (16 tiles) + intra-wave transpose + G partial accumulate ----
  f32x4 d00 = {0, 0, 0, 0}, d01 = {0, 0, 0, 0}, d11 = {0, 0, 0, 0};
  const int sx = li & 7;
#pragma unroll 1
  for (int t = 0; t < 16; ++t) {
    const int T = 16 * w + t;
    const f16x8 Whi = __builtin_bit_cast(f16x8, wf[T * 64 + l]);
    const f16x8 Wlo = __builtin_bit_cast(f16x8, wf[(32 + T) * 64 + l]);
    f32x4 a0 = {0, 0, 0, 0}, a1 = {0, 0, 0, 0};
    a0 = MFMA32(X0.hi, Whi, a0); a0 = MFMA32(X0.hi, Wlo, a0); a0 = MFMA32(X0.lo, Whi, a0);
    a1 = MFMA32(X1.hi, Whi, a1); a1 = MFMA32(X1.hi, Wlo, a1); a1 = MFMA32(X1.lo, Whi, a1);
    const float bv = bias[16 * T + li];
    float4 h0, h1;
    h0.x = sigm(a0[0] + bv); h0.y = sigm(a0[1] + bv);
    h0.z = sigm(a0[2] + bv); h0.w = sigm(a0[3] + bv);
    h1.x = (16 + 4 * gl + 0 < 28) ? sigm(a1[0] + bv) : 0.0f;
    h1.y = (16 + 4 * gl + 1 < 28) ? sigm(a1[1] + bv) : 0.0f;
    h1.z = (16 + 4 * gl + 2 < 28) ? sigm(a1[2] + bv) : 0.0f;
    h1.w = (16 + 4 * gl + 3 < 28) ? sigm(a1[3] + bv) : 0.0f;
    // transpose store: single buffer [16 cols][32 rows], granule-swizzled
    // (same-wave DS ops execute in order -> no double-buffer needed)
    *reinterpret_cast<float4*>(&sm[wb + li * 32 + ((gl ^ sx) << 2)]) = h0;
    *reinterpret_cast<float4*>(&sm[wb + li * 32 + (((4 + gl) ^ sx) << 2)]) = h1;
    float a0e[4], a1e[4];
#pragma unroll
    for (int e = 0; e < 4; ++e) {
      const int c = 4 * gl + e;
      const int base = wb + c * 32 + (li & 3);
      a0e[e] = sm[base + ((((li >> 2)    ) ^ (c & 7)) << 2)];
      a1e[e] = sm[base + ((((li >> 2) + 4) ^ (c & 7)) << 2)];
    }
    const P8 A0 = split4(a0e[0], a0e[1], a0e[2], a0e[3]);
    const P8 A1 = split4(a1e[0], a1e[1], a1e[2], a1e[3]);
    d00 = MFMA16(A0.hi, A0.hi, d00); d00 = MFMA16(A0.hi, A0.lo, d00); d00 = MFMA16(A0.lo, A0.hi, d00);
    d01 = MFMA16(A0.hi, A1.hi, d01); d01 = MFMA16(A0.hi, A1.lo, d01); d01 = MFMA16(A0.lo, A1.hi, d01);
    d11 = MFMA16(A1.hi, A1.hi, d11); d11 = MFMA16(A1.hi, A1.lo, d11); d11 = MFMA16(A1.lo, A1.hi, d11);
  }

  // ---- 4. park partials; ONE barrier; sum partner's ----
  {
    const int pk = wb + 1024 + l * 12;
    *reinterpret_cast<float4*>(&sm[pk + 0]) = float4{d00[0], d00[1], d00[2], d00[3]};
    *reinterpret_cast<float4*>(&sm[pk + 4]) = float4{d01[0], d01[1], d01[2], d01[3]};
    *reinterpret_cast<float4*>(&sm[pk + 8]) = float4{d11[0], d11[1], d11[2], d11[3]};
  }
  __syncthreads();
  {
    const int pk = pb + 1024 + l * 12;
    const float4 u = *reinterpret_cast<const float4*>(&sm[pk + 0]);
    const float4 v = *reinterpret_cast<const float4*>(&sm[pk + 4]);
    const float4 t = *reinterpret_cast<const float4*>(&sm[pk + 8]);
    d00[0] += u.x; d00[1] += u.y; d00[2] += u.z; d00[3] += u.w;
    d01[0] += v.x; d01[1] += v.y; d01[2] += v.z; d01[3] += v.w;
    d11[0] += t.x; d11[1] += t.y; d11[2] += t.z; d11[3] += t.w;
  }

  // ---- 5. Gc (+mirror) into own [0,896) ----
#pragma unroll
  for (int i = 0; i < 4; ++i) {
    const int ra = 4 * gl + i;
    sm[wb + ra * 32 + li] = d00[i];
    sm[wb + li * 32 + ra] = d00[i];
    sm[wb + ra * 32 + 16 + li] = d01[i];
    sm[wb + (16 + li) * 32 + ra] = d01[i];
    sm[wb + (16 + ra) * 32 + 16 + li] = d11[i];
    sm[wb + (16 + li) * 32 + 16 + ra] = d11[i];
  }

  // ---- 6. solve G Y = x : per-wave Gauss-Jordan (duplicated; no sync) ----
  {
    const int j = l;
    float col[28];
#pragma unroll
    for (int r = 0; r < 28; ++r) {
      float v = 0.f;
      if (j < 28)      v = sm[wb + r * 32 + j];
      else if (j < 56) v = xi[r * 28 + (j - 28)];
      col[r] = v;
    }
#pragma unroll
    for (int k = 0; k < 28; ++k) {
      const float piv = __shfl(col[k], k);
      const float pivinv = 1.0f / piv;
      col[k] *= pivinv;
#pragma unroll
      for (int r2 = 0; r2 < 28; ++r2) {
        if (r2 == k) continue;
        const float m = __shfl(col[r2], k);
        col[r2] -= m * col[k];
      }
    }
    // Y^T into own [0,1024); zero pads
    if (j >= 28 && j < 56) {
      const int c = j - 28;
#pragma unroll
      for (int r2 = 0; r2 < 28; ++r2) sm[wb + c * 32 + r2] = col[r2];
      *reinterpret_cast<float4*>(&sm[wb + c * 32 + 28]) = z4;
    }
    if (j >= 56) {                     // zero pad rows 28..31
      const int rr = 28 + ((j - 56) >> 1), half = (j - 56) & 1;
#pragma unroll
      for (int t = 0; t < 4; ++t)
        *reinterpret_cast<float4*>(&sm[wb + rr * 32 + half * 16 + 4 * t]) = z4;
    }
  }

  // ---- 7. Y A-fragments ----
  const P16 Y0 = split16(*reinterpret_cast<const float4*>(&sm[wb + li * 32 + 4 * gl]),
                         *reinterpret_cast<const float4*>(&sm[wb + li * 32 + 16 + 4 * gl]));
  const P16 Y1 = split16(*reinterpret_cast<const float4*>(&sm[wb + (16 + li) * 32 + 4 * gl]),
                         *reinterpret_cast<const float4*>(&sm[wb + (16 + li) * 32 + 16 + 4 * gl]));

  // ---- 8. B = H~^T Y : recompute H per tile (16 tiles); direct stores ----
  float* Bo = Bout + (size_t)n * 14336;
#pragma unroll 1
  for (int t = 0; t < 16; ++t) {
    const int T = 16 * w + t;
    const f16x8 Whi = __builtin_bit_cast(f16x8, wf[T * 64 + l]);
    const f16x8 Wlo = __builtin_bit_cast(f16x8, wf[(32 + T) * 64 + l]);
    f32x4 a0 = {0, 0, 0, 0}, a1 = {0, 0, 0, 0};
    a0 = MFMA32(X0.hi, Whi, a0); a0 = MFMA32(X0.hi, Wlo, a0); a0 = MFMA32(X0.lo, Whi, a0);
    a1 = MFMA32(X1.hi, Whi, a1); a1 = MFMA32(X1.hi, Wlo, a1); a1 = MFMA32(X1.lo, Whi, a1);
    const float bv = bias[16 * T + li];
    f16x8 Bhi, Blo;
#pragma unroll
    for (int i = 0; i < 4; ++i) {
      const float h0 = sigm(a0[i] + bv);
      const _Float16 hh0 = (_Float16)h0;
      Bhi[i] = hh0; Blo[i] = (_Float16)(h0 - (float)hh0);
      const float h1 = (16 + 4 * gl + i < 28) ? sigm(a1[i] + bv) : 0.0f;
      const _Float16 hh1 = (_Float16)h1;
      Bhi[4 + i] = hh1; Blo[4 + i] = (_Float16)(h1 - (float)hh1);
    }
    f32x4 bt0 = {0, 0, 0, 0}, bt1 = {0, 0, 0, 0};
    bt0 = MFMA32(Y0.hi, Bhi, bt0); bt0 = MFMA32(Y0.hi, Blo, bt0); bt0 = MFMA32(Y0.lo, Bhi, bt0);
    bt1 = MFMA32(Y1.hi, Bhi, bt1); bt1 = MFMA32(Y1.hi, Blo, bt1); bt1 = MFMA32(Y1.lo, Bhi, bt1);
    float* Brow = Bo + (16 * T + li) * 28;
    *reinterpret_cast<float4*>(Brow + 4 * gl) = float4{bt0[0], bt0[1], bt0[2], bt0[3]};
    if (gl < 3)
      *reinterpret_cast<float4*>(Brow + 16 + 4 * gl) = float4{bt1[0], bt1[1], bt1[2], bt1[3]};
  }
}

extern "C" void kernel_launch(void* const* d_in, const int* in_sizes, int n_in,
                              void* d_out, int out_size, void* d_ws, size_t ws_size,
                              hipStream_t stream) {
  const float* x = (const float*)d_in[0];
  const float* W = (const float*)d_in[1];
  const float* b = (const float*)d_in[2];
  const int N = in_sizes[0] / 784;               // 4096 samples
  float* Xout = (float*)d_out;                   // [N,1,28,28]
  float* Bout = Xout + (size_t)N * 784;          // [N,1,512,28]
  uint4* wf = (uint4*)d_ws;                      // 65536 B
  prep_wfrag<<<8, 256, 0, stream>>>(W, wf);
  elm_kernel<<<N, 128, 0, stream>>>(x, wf, b, Xout, Bout);
}

// Round 14
// 133.675 us; speedup vs baseline: 1.3578x; 1.3578x over previous
//
#include <hip/hip_runtime.h>

typedef _Float16 f16x8 __attribute__((ext_vector_type(8)));
typedef _Float16 f16x4 __attribute__((ext_vector_type(4)));
typedef float f32x4 __attribute__((ext_vector_type(4)));

#define MFMA32(A, B, C) __builtin_amdgcn_mfma_f32_16x16x32_f16(A, B, C, 0, 0, 0)
#define MFMA16(A, B, C) __builtin_amdgcn_mfma_f32_16x16x16f16(A, B, C, 0, 0, 0)

struct P16 { f16x8 hi, lo; };
struct P8  { f16x4 hi, lo; };

__device__ __forceinline__ P16 split16(float4 a, float4 b) {
  float v[8] = {a.x, a.y, a.z, a.w, b.x, b.y, b.z, b.w};
  P16 p;
#pragma unroll
  for (int e = 0; e < 8; ++e) {
    const _Float16 h = (_Float16)v[e];
    p.hi[e] = h; p.lo[e] = (_Float16)(v[e] - (float)h);
  }
  return p;
}
__device__ __forceinline__ P8 split4(float a0, float a1, float a2, float a3) {
  float v[4] = {a0, a1, a2, a3};
  P8 p;
#pragma unroll
  for (int e = 0; e < 4; ++e) {
    const _Float16 h = (_Float16)v[e];
    p.hi[e] = h; p.lo[e] = (_Float16)(v[e] - (float)h);
  }
  return p;
}
__device__ __forceinline__ float sigm(float a) {
  return __builtin_amdgcn_rcpf(1.0f + __expf(-a));
}

// W [512][28] f32 -> f16 hi/lo fragment planes: wf[{0,1}*32 + T][lane] = uint4
// element e: k = 4g+e (e<4) | 16+4g+(e-4), g=lane>>4; W-col = 16T + (lane&15)
__global__ void prep_wfrag(const float* __restrict__ W, uint4* __restrict__ wf) {
  const int id = blockIdx.x * 256 + threadIdx.x;
  if (id >= 2048) return;
  const int T = id >> 6, l = id & 63, g = (l >> 4) & 3, li = l & 15;
  const int col = 16 * T + li;
  unsigned hi[8], lo[8];
#pragma unroll
  for (int e = 0; e < 8; ++e) {
    const int k = (e < 4) ? (4 * g + e) : (16 + 4 * g + (e - 4));
    const float v = (k < 28) ? W[col * 28 + k] : 0.0f;
    const _Float16 h = (_Float16)v;
    const _Float16 lw = (_Float16)(v - (float)h);
    hi[e] = __builtin_bit_cast(unsigned short, h);
    lo[e] = __builtin_bit_cast(unsigned short, lw);
  }
  uint4 uh, ul;
  uh.x = hi[0] | (hi[1] << 16); uh.y = hi[2] | (hi[3] << 16);
  uh.z = hi[4] | (hi[5] << 16); uh.w = hi[6] | (hi[7] << 16);
  ul.x = lo[0] | (lo[1] << 16); ul.y = lo[2] | (lo[3] << 16);
  ul.z = lo[4] | (lo[5] << 16); ul.w = lo[6] | (lo[7] << 16);
  wf[T * 64 + l] = uh;
  wf[(32 + T) * 64 + l] = ul;
}

// TWO WAVES = ONE SAMPLE; 128-thread blocks; exactly ONE __syncthreads.
// __launch_bounds__(128,4): 128-reg cap -- the session-proven spill-free bound
// (cap 85 spilled in R6/R7/R13; cap 128 clean in R8/R12).
// Wave w handles H/B tiles 16w..16w+15. G partials exchanged via LDS park:
//   per-wave region (1792 words): [0,512) transpose buf (G phase)
//                                 [0,896)  Gc (post-barrier; transpose dead)
//                                 [0,1024) Yt (post-solve; Gc dead)
//                                 [1024,1792) parked G partials
// Solve duplicated per wave (cheaper than a second sync). X = x (full row-rank).
// B = H^T Y with H recomputed per tile (C-frag == B-operand frag), direct stores.
__global__ __launch_bounds__(128, 4) void elm_kernel(
    const float* __restrict__ x, const uint4* __restrict__ wf,
    const float* __restrict__ bias, float* __restrict__ Xout,
    float* __restrict__ Bout)
{
  __shared__ __align__(16) float sm[3584];   // 14336 B: 2 x 1792-word wave regions
  const int tid = threadIdx.x, n = blockIdx.x;
  const int w = tid >> 6, l = tid & 63, gl = l >> 4, li = l & 15;
  const int wb = w * 1792, pb = (w ^ 1) * 1792;
  const float* xi = x + (size_t)n * 784;

  // ---- 1. X = x (both waves share the copy) ----
  {
    const float4* x4 = reinterpret_cast<const float4*>(xi);
    float4* X4 = reinterpret_cast<float4*>(Xout + (size_t)n * 784);
#pragma unroll
    for (int k = 0; k < 2; ++k) {
      const int idx = tid + 128 * k;
      if (idx < 196) X4[idx] = x4[idx];
    }
  }

  // ---- 2. x A-fragments direct from global (row stride 112B, 16B-aligned) ----
  const float4 z4 = {0, 0, 0, 0};
  const float4 xa0 = *reinterpret_cast<const float4*>(xi + li * 28 + 4 * gl);
  const float4 xb0 = (gl < 3) ? *reinterpret_cast<const float4*>(xi + li * 28 + 16 + 4 * gl) : z4;
  const int r1 = (li < 12) ? 16 + li : 0;
  float4 xa1 = *reinterpret_cast<const float4*>(xi + r1 * 28 + 4 * gl);
  float4 xb1 = (gl < 3) ? *reinterpret_cast<const float4*>(xi + r1 * 28 + 16 + 4 * gl) : z4;
  if (li >= 12) { xa1 = z4; xb1 = z4; }
  const P16 X0 = split16(xa0, xb0);
  const P16 X1 = split16(xa1, xb1);

  // ---- 3. H (16 tiles) + intra-wave transpose + G partial accumulate ----
  f32x4 d00 = {0, 0, 0, 0}, d01 = {0, 0, 0, 0}, d11 = {0, 0, 0, 0};
  const int sx = li & 7;
#pragma unroll 1
  for (int t = 0; t < 16; ++t) {
    const int T = 16 * w + t;
    const f16x8 Whi = __builtin_bit_cast(f16x8, wf[T * 64 + l]);
    const f16x8 Wlo = __builtin_bit_cast(f16x8, wf[(32 + T) * 64 + l]);
    f32x4 a0 = {0, 0, 0, 0}, a1 = {0, 0, 0, 0};
    a0 = MFMA32(X0.hi, Whi, a0); a0 = MFMA32(X0.hi, Wlo, a0); a0 = MFMA32(X0.lo, Whi, a0);
    a1 = MFMA32(X1.hi, Whi, a1); a1 = MFMA32(X1.hi, Wlo, a1); a1 = MFMA32(X1.lo, Whi, a1);
    const float bv = bias[16 * T + li];
    float4 h0, h1;
    h0.x = sigm(a0[0] + bv); h0.y = sigm(a0[1] + bv);
    h0.z = sigm(a0[2] + bv); h0.w = sigm(a0[3] + bv);
    h1.x = (16 + 4 * gl + 0 < 28) ? sigm(a1[0] + bv) : 0.0f;
    h1.y = (16 + 4 * gl + 1 < 28) ? sigm(a1[1] + bv) : 0.0f;
    h1.z = (16 + 4 * gl + 2 < 28) ? sigm(a1[2] + bv) : 0.0f;
    h1.w = (16 + 4 * gl + 3 < 28) ? sigm(a1[3] + bv) : 0.0f;
    // transpose store: single buffer [16 cols][32 rows], granule-swizzled
    *reinterpret_cast<float4*>(&sm[wb + li * 32 + ((gl ^ sx) << 2)]) = h0;
    *reinterpret_cast<float4*>(&sm[wb + li * 32 + (((4 + gl) ^ sx) << 2)]) = h1;
    float a0e[4], a1e[4];
#pragma unroll
    for (int e = 0; e < 4; ++e) {
      const int c = 4 * gl + e;
      const int base = wb + c * 32 + (li & 3);
      a0e[e] = sm[base + ((((li >> 2)    ) ^ (c & 7)) << 2)];
      a1e[e] = sm[base + ((((li >> 2) + 4) ^ (c & 7)) << 2)];
    }
    const P8 A0 = split4(a0e[0], a0e[1], a0e[2], a0e[3]);
    const P8 A1 = split4(a1e[0], a1e[1], a1e[2], a1e[3]);
    d00 = MFMA16(A0.hi, A0.hi, d00); d00 = MFMA16(A0.hi, A0.lo, d00); d00 = MFMA16(A0.lo, A0.hi, d00);
    d01 = MFMA16(A0.hi, A1.hi, d01); d01 = MFMA16(A0.hi, A1.lo, d01); d01 = MFMA16(A0.lo, A1.hi, d01);
    d11 = MFMA16(A1.hi, A1.hi, d11); d11 = MFMA16(A1.hi, A1.lo, d11); d11 = MFMA16(A1.lo, A1.hi, d11);
  }

  // ---- 4. park partials; ONE barrier; sum partner's ----
  {
    const int pk = wb + 1024 + l * 12;
    *reinterpret_cast<float4*>(&sm[pk + 0]) = float4{d00[0], d00[1], d00[2], d00[3]};
    *reinterpret_cast<float4*>(&sm[pk + 4]) = float4{d01[0], d01[1], d01[2], d01[3]};
    *reinterpret_cast<float4*>(&sm[pk + 8]) = float4{d11[0], d11[1], d11[2], d11[3]};
  }
  __syncthreads();
  {
    const int pk = pb + 1024 + l * 12;
    const float4 u = *reinterpret_cast<const float4*>(&sm[pk + 0]);
    const float4 v = *reinterpret_cast<const float4*>(&sm[pk + 4]);
    const float4 t = *reinterpret_cast<const float4*>(&sm[pk + 8]);
    d00[0] += u.x; d00[1] += u.y; d00[2] += u.z; d00[3] += u.w;
    d01[0] += v.x; d01[1] += v.y; d01[2] += v.z; d01[3] += v.w;
    d11[0] += t.x; d11[1] += t.y; d11[2] += t.z; d11[3] += t.w;
  }

  // ---- 5. Gc (+mirror) into own [0,896) ----
#pragma unroll
  for (int i = 0; i < 4; ++i) {
    const int ra = 4 * gl + i;
    sm[wb + ra * 32 + li] = d00[i];
    sm[wb + li * 32 + ra] = d00[i];
    sm[wb + ra * 32 + 16 + li] = d01[i];
    sm[wb + (16 + li) * 32 + ra] = d01[i];
    sm[wb + (16 + ra) * 32 + 16 + li] = d11[i];
    sm[wb + (16 + li) * 32 + 16 + ra] = d11[i];
  }

  // ---- 6. solve G Y = x : per-wave Gauss-Jordan (duplicated; no sync) ----
  {
    const int j = l;
    float col[28];
#pragma unroll
    for (int r = 0; r < 28; ++r) {
      float v = 0.f;
      if (j < 28)      v = sm[wb + r * 32 + j];
      else if (j < 56) v = xi[r * 28 + (j - 28)];
      col[r] = v;
    }
#pragma unroll
    for (int k = 0; k < 28; ++k) {
      const float piv = __shfl(col[k], k);
      const float pivinv = 1.0f / piv;
      col[k] *= pivinv;
#pragma unroll
      for (int r2 = 0; r2 < 28; ++r2) {
        if (r2 == k) continue;
        const float m = __shfl(col[r2], k);
        col[r2] -= m * col[k];
      }
    }
    // Y^T into own [0,1024); zero pads
    if (j >= 28 && j < 56) {
      const int c = j - 28;
#pragma unroll
      for (int r2 = 0; r2 < 28; ++r2) sm[wb + c * 32 + r2] = col[r2];
      *reinterpret_cast<float4*>(&sm[wb + c * 32 + 28]) = z4;
    }
    if (j >= 56) {                     // zero pad rows 28..31
      const int rr = 28 + ((j - 56) >> 1), half = (j - 56) & 1;
#pragma unroll
      for (int t = 0; t < 4; ++t)
        *reinterpret_cast<float4*>(&sm[wb + rr * 32 + half * 16 + 4 * t]) = z4;
    }
  }

  // ---- 7. Y A-fragments ----
  const P16 Y0 = split16(*reinterpret_cast<const float4*>(&sm[wb + li * 32 + 4 * gl]),
                         *reinterpret_cast<const float4*>(&sm[wb + li * 32 + 16 + 4 * gl]));
  const P16 Y1 = split16(*reinterpret_cast<const float4*>(&sm[wb + (16 + li) * 32 + 4 * gl]),
                         *reinterpret_cast<const float4*>(&sm[wb + (16 + li) * 32 + 16 + 4 * gl]));

  // ---- 8. B = H~^T Y : recompute H per tile (16 tiles); direct stores ----
  float* Bo = Bout + (size_t)n * 14336;
#pragma unroll 1
  for (int t = 0; t < 16; ++t) {
    const int T = 16 * w + t;
    const f16x8 Whi = __builtin_bit_cast(f16x8, wf[T * 64 + l]);
    const f16x8 Wlo = __builtin_bit_cast(f16x8, wf[(32 + T) * 64 + l]);
    f32x4 a0 = {0, 0, 0, 0}, a1 = {0, 0, 0, 0};
    a0 = MFMA32(X0.hi, Whi, a0); a0 = MFMA32(X0.hi, Wlo, a0); a0 = MFMA32(X0.lo, Whi, a0);
    a1 = MFMA32(X1.hi, Whi, a1); a1 = MFMA32(X1.hi, Wlo, a1); a1 = MFMA32(X1.lo, Whi, a1);
    const float bv = bias[16 * T + li];
    f16x8 Bhi, Blo;
#pragma unroll
    for (int i = 0; i < 4; ++i) {
      const float h0 = sigm(a0[i] + bv);
      const _Float16 hh0 = (_Float16)h0;
      Bhi[i] = hh0; Blo[i] = (_Float16)(h0 - (float)hh0);
      const float h1 = (16 + 4 * gl + i < 28) ? sigm(a1[i] + bv) : 0.0f;
      const _Float16 hh1 = (_Float16)h1;
      Bhi[4 + i] = hh1; Blo[4 + i] = (_Float16)(h1 - (float)hh1);
    }
    f32x4 bt0 = {0, 0, 0, 0}, bt1 = {0, 0, 0, 0};
    bt0 = MFMA32(Y0.hi, Bhi, bt0); bt0 = MFMA32(Y0.hi, Blo, bt0); bt0 = MFMA32(Y0.lo, Bhi, bt0);
    bt1 = MFMA32(Y1.hi, Bhi, bt1); bt1 = MFMA32(Y1.hi, Blo, bt1); bt1 = MFMA32(Y1.lo, Bhi, bt1);
    float* Brow = Bo + (16 * T + li) * 28;
    *reinterpret_cast<float4*>(Brow + 4 * gl) = float4{bt0[0], bt0[1], bt0[2], bt0[3]};
    if (gl < 3)
      *reinterpret_cast<float4*>(Brow + 16 + 4 * gl) = float4{bt1[0], bt1[1], bt1[2], bt1[3]};
  }
}

extern "C" void kernel_launch(void* const* d_in, const int* in_sizes, int n_in,
                              void* d_out, int out_size, void* d_ws, size_t ws_size,
                              hipStream_t stream) {
  const float* x = (const float*)d_in[0];
  const float* W = (const float*)d_in[1];
  const float* b = (const float*)d_in[2];
  const int N = in_sizes[0] / 784;               // 4096 samples
  float* Xout = (float*)d_out;                   // [N,1,28,28]
  float* Bout = Xout + (size_t)N * 784;          // [N,1,512,28]
  uint4* wf = (uint4*)d_ws;                      // 65536 B
  prep_wfrag<<<8, 256, 0, stream>>>(W, wf);
  elm_kernel<<<N, 128, 0, stream>>>(x, wf, b, Xout, Bout);
}

// Round 15
// 111.382 us; speedup vs baseline: 1.6296x; 1.2001x over previous
//
#include <hip/hip_runtime.h>

typedef _Float16 f16x8 __attribute__((ext_vector_type(8)));
typedef _Float16 f16x4 __attribute__((ext_vector_type(4)));
typedef float f32x4 __attribute__((ext_vector_type(4)));

#define MFMA32(A, B, C) __builtin_amdgcn_mfma_f32_16x16x32_f16(A, B, C, 0, 0, 0)
#define MFMA16(A, B, C) __builtin_amdgcn_mfma_f32_16x16x16f16(A, B, C, 0, 0, 0)

struct P16 { f16x8 hi, lo; };
struct P8  { f16x4 hi, lo; };

__device__ __forceinline__ P16 split16(float4 a, float4 b) {
  float v[8] = {a.x, a.y, a.z, a.w, b.x, b.y, b.z, b.w};
  P16 p;
#pragma unroll
  for (int e = 0; e < 8; ++e) {
    const _Float16 h = (_Float16)v[e];
    p.hi[e] = h; p.lo[e] = (_Float16)(v[e] - (float)h);
  }
  return p;
}
__device__ __forceinline__ P8 split4(float a0, float a1, float a2, float a3) {
  float v[4] = {a0, a1, a2, a3};
  P8 p;
#pragma unroll
  for (int e = 0; e < 4; ++e) {
    const _Float16 h = (_Float16)v[e];
    p.hi[e] = h; p.lo[e] = (_Float16)(v[e] - (float)h);
  }
  return p;
}
__device__ __forceinline__ float sigm(float a) {
  return __builtin_amdgcn_rcpf(1.0f + __expf(-a));
}

// W [512][28] f32 -> f16 hi/lo fragment planes: wf[{0,1}*32 + T][lane] = uint4
// element e: k = 4g+e (e<4) | 16+4g+(e-4), g=lane>>4; W-col = 16T + (lane&15)
__global__ void prep_wfrag(const float* __restrict__ W, uint4* __restrict__ wf) {
  const int id = blockIdx.x * 256 + threadIdx.x;
  if (id >= 2048) return;
  const int T = id >> 6, l = id & 63, g = (l >> 4) & 3, li = l & 15;
  const int col = 16 * T + li;
  unsigned hi[8], lo[8];
#pragma unroll
  for (int e = 0; e < 8; ++e) {
    const int k = (e < 4) ? (4 * g + e) : (16 + 4 * g + (e - 4));
    const float v = (k < 28) ? W[col * 28 + k] : 0.0f;
    const _Float16 h = (_Float16)v;
    const _Float16 lw = (_Float16)(v - (float)h);
    hi[e] = __builtin_bit_cast(unsigned short, h);
    lo[e] = __builtin_bit_cast(unsigned short, lw);
  }
  uint4 uh, ul;
  uh.x = hi[0] | (hi[1] << 16); uh.y = hi[2] | (hi[3] << 16);
  uh.z = hi[4] | (hi[5] << 16); uh.w = hi[6] | (hi[7] << 16);
  ul.x = lo[0] | (lo[1] << 16); ul.y = lo[2] | (lo[3] << 16);
  ul.z = lo[4] | (lo[5] << 16); ul.w = lo[6] | (lo[7] << 16);
  wf[T * 64 + l] = uh;
  wf[(32 + T) * 64 + l] = ul;
}

// ONE WAVE = ONE SAMPLE (R12 structure, best measured: 116 us) + UNROLL-2 ILP:
// grid supplies exactly one wave-generation per CU (4096 waves = 4/SIMD), so
// dur == single-wave critical path. unroll-2 interleaves two independent
// tile-chains (the (T&1) transpose double-buffer exists for exactly this),
// hiding MFMA<->VALU<->DS latency within a wave. ZERO __syncthreads.
__global__ __launch_bounds__(256, 4) void elm_kernel(
    const float* __restrict__ x, const uint4* __restrict__ wf,
    const float* __restrict__ bias, float* __restrict__ Xout,
    float* __restrict__ Bout)
{
  __shared__ __align__(16) float sm[4096];   // 16 KB: 4 x 1024-word wave regions
  const int tid = threadIdx.x;
  const int w = tid >> 6, l = tid & 63, gl = l >> 4, li = l & 15;
  const int n = blockIdx.x * 4 + w;          // sample owned by this wave
  const int wb = w * 1024;
  const float* xi = x + (size_t)n * 784;

  // ---- 1. X = x (coalesced per-wave copy) ----
  {
    const float4* x4 = reinterpret_cast<const float4*>(xi);
    float4* X4 = reinterpret_cast<float4*>(Xout + (size_t)n * 784);
#pragma unroll
    for (int k = 0; k < 4; ++k) {
      const int idx = l + 64 * k;
      if (idx < 196) X4[idx] = x4[idx];
    }
  }

  // ---- 2. x A-fragments direct from global (row stride 112B = 16B-aligned) ----
  const float4 z4 = {0, 0, 0, 0};
  const float4 xa0 = *reinterpret_cast<const float4*>(xi + li * 28 + 4 * gl);
  const float4 xb0 = (gl < 3) ? *reinterpret_cast<const float4*>(xi + li * 28 + 16 + 4 * gl) : z4;
  const int r1 = (li < 12) ? 16 + li : 0;    // clamp to stay in-bounds
  float4 xa1 = *reinterpret_cast<const float4*>(xi + r1 * 28 + 4 * gl);
  float4 xb1 = (gl < 3) ? *reinterpret_cast<const float4*>(xi + r1 * 28 + 16 + 4 * gl) : z4;
  if (li >= 12) { xa1 = z4; xb1 = z4; }
  const P16 X0 = split16(xa0, xb0);
  const P16 X1 = split16(xa1, xb1);

  // ---- 3. H (32 tiles) + intra-wave transpose + G accumulate, UNROLL 2 ----
  f32x4 d00 = {0, 0, 0, 0}, d01 = {0, 0, 0, 0}, d11 = {0, 0, 0, 0};
  const int sx = li & 7;
#pragma unroll 2
  for (int T = 0; T < 32; ++T) {
    const f16x8 Whi = __builtin_bit_cast(f16x8, wf[T * 64 + l]);
    const f16x8 Wlo = __builtin_bit_cast(f16x8, wf[(32 + T) * 64 + l]);
    f32x4 a0 = {0, 0, 0, 0}, a1 = {0, 0, 0, 0};
    a0 = MFMA32(X0.hi, Whi, a0); a0 = MFMA32(X0.hi, Wlo, a0); a0 = MFMA32(X0.lo, Whi, a0);
    a1 = MFMA32(X1.hi, Whi, a1); a1 = MFMA32(X1.hi, Wlo, a1); a1 = MFMA32(X1.lo, Whi, a1);
    const float bv = bias[16 * T + li];
    float4 h0, h1;
    h0.x = sigm(a0[0] + bv); h0.y = sigm(a0[1] + bv);
    h0.z = sigm(a0[2] + bv); h0.w = sigm(a0[3] + bv);
    h1.x = (16 + 4 * gl + 0 < 28) ? sigm(a1[0] + bv) : 0.0f;
    h1.y = (16 + 4 * gl + 1 < 28) ? sigm(a1[1] + bv) : 0.0f;
    h1.z = (16 + 4 * gl + 2 < 28) ? sigm(a1[2] + bv) : 0.0f;
    h1.w = (16 + 4 * gl + 3 < 28) ? sigm(a1[3] + bv) : 0.0f;
    // transpose store: buffer [16 cols][32 rows], granule-swizzled, dbuf by T&1
    const int tb = wb + (T & 1) * 512;
    *reinterpret_cast<float4*>(&sm[tb + li * 32 + ((gl ^ sx) << 2)]) = h0;
    *reinterpret_cast<float4*>(&sm[tb + li * 32 + (((4 + gl) ^ sx) << 2)]) = h1;
    // transpose read: A0 row li, A1 row 16+li, cols c = 4gl+e
    float a0e[4], a1e[4];
#pragma unroll
    for (int e = 0; e < 4; ++e) {
      const int c = 4 * gl + e;
      const int base = tb + c * 32 + (li & 3);
      a0e[e] = sm[base + ((((li >> 2)    ) ^ (c & 7)) << 2)];
      a1e[e] = sm[base + ((((li >> 2) + 4) ^ (c & 7)) << 2)];
    }
    const P8 A0 = split4(a0e[0], a0e[1], a0e[2], a0e[3]);
    const P8 A1 = split4(a1e[0], a1e[1], a1e[2], a1e[3]);
    d00 = MFMA16(A0.hi, A0.hi, d00); d00 = MFMA16(A0.hi, A0.lo, d00); d00 = MFMA16(A0.lo, A0.hi, d00);
    d01 = MFMA16(A0.hi, A1.hi, d01); d01 = MFMA16(A0.hi, A1.lo, d01); d01 = MFMA16(A0.lo, A1.hi, d01);
    d11 = MFMA16(A1.hi, A1.hi, d11); d11 = MFMA16(A1.hi, A1.lo, d11); d11 = MFMA16(A1.lo, A1.hi, d11);
  }

  // ---- 4. G fragments -> per-wave LDS Gc[r*32+c] (+ symmetric mirror) ----
#pragma unroll
  for (int i = 0; i < 4; ++i) {
    const int ra = 4 * gl + i;
    sm[wb + ra * 32 + li] = d00[i];
    sm[wb + li * 32 + ra] = d00[i];
    sm[wb + ra * 32 + 16 + li] = d01[i];
    sm[wb + (16 + li) * 32 + ra] = d01[i];
    sm[wb + (16 + ra) * 32 + 16 + li] = d11[i];
    sm[wb + (16 + li) * 32 + 16 + ra] = d11[i];
  }

  // ---- 5. solve G Y = x : per-wave Gauss-Jordan; RHS from global x ----
  {
    const int j = l;
    float col[28];
#pragma unroll
    for (int r = 0; r < 28; ++r) {
      float v = 0.f;
      if (j < 28)      v = sm[wb + r * 32 + j];
      else if (j < 56) v = xi[r * 28 + (j - 28)];
      col[r] = v;
    }
#pragma unroll
    for (int k = 0; k < 28; ++k) {
      const float piv = __shfl(col[k], k);
      const float pivinv = 1.0f / piv;
      col[k] *= pivinv;
#pragma unroll
      for (int r2 = 0; r2 < 28; ++r2) {
        if (r2 == k) continue;
        const float m = __shfl(col[r2], k);
        col[r2] -= m * col[k];
      }
    }
    // Y^T into wb[0,1024): Yt[c][a] = col[a]; zero col-pads 28..31
    if (j >= 28 && j < 56) {
      const int c = j - 28;
#pragma unroll
      for (int r2 = 0; r2 < 28; ++r2) sm[wb + c * 32 + r2] = col[r2];
      *reinterpret_cast<float4*>(&sm[wb + c * 32 + 28]) = z4;
    }
    if (j >= 56) {                     // zero pad rows 28..31 (2 lanes/row)
      const int rr = 28 + ((j - 56) >> 1), half = (j - 56) & 1;
#pragma unroll
      for (int t = 0; t < 4; ++t)
        *reinterpret_cast<float4*>(&sm[wb + rr * 32 + half * 16 + 4 * t]) = z4;
    }
  }

  // ---- 6. Y A-fragments from per-wave Yt ----
  const P16 Y0 = split16(*reinterpret_cast<const float4*>(&sm[wb + li * 32 + 4 * gl]),
                         *reinterpret_cast<const float4*>(&sm[wb + li * 32 + 16 + 4 * gl]));
  const P16 Y1 = split16(*reinterpret_cast<const float4*>(&sm[wb + (16 + li) * 32 + 4 * gl]),
                         *reinterpret_cast<const float4*>(&sm[wb + (16 + li) * 32 + 16 + 4 * gl]));

  // ---- 7. B = H~^T Y : recompute H per tile; direct stores; UNROLL 2 ----
  float* Bo = Bout + (size_t)n * 14336;
#pragma unroll 2
  for (int T = 0; T < 32; ++T) {
    const f16x8 Whi = __builtin_bit_cast(f16x8, wf[T * 64 + l]);
    const f16x8 Wlo = __builtin_bit_cast(f16x8, wf[(32 + T) * 64 + l]);
    f32x4 a0 = {0, 0, 0, 0}, a1 = {0, 0, 0, 0};
    a0 = MFMA32(X0.hi, Whi, a0); a0 = MFMA32(X0.hi, Wlo, a0); a0 = MFMA32(X0.lo, Whi, a0);
    a1 = MFMA32(X1.hi, Whi, a1); a1 = MFMA32(X1.hi, Wlo, a1); a1 = MFMA32(X1.lo, Whi, a1);
    const float bv = bias[16 * T + li];
    f16x8 Bhi, Blo;
#pragma unroll
    for (int i = 0; i < 4; ++i) {
      const float h0 = sigm(a0[i] + bv);
      const _Float16 hh0 = (_Float16)h0;
      Bhi[i] = hh0; Blo[i] = (_Float16)(h0 - (float)hh0);
      const float h1 = (16 + 4 * gl + i < 28) ? sigm(a1[i] + bv) : 0.0f;
      const _Float16 hh1 = (_Float16)h1;
      Bhi[4 + i] = hh1; Blo[4 + i] = (_Float16)(h1 - (float)hh1);
    }
    f32x4 bt0 = {0, 0, 0, 0}, bt1 = {0, 0, 0, 0};
    bt0 = MFMA32(Y0.hi, Bhi, bt0); bt0 = MFMA32(Y0.hi, Blo, bt0); bt0 = MFMA32(Y0.lo, Bhi, bt0);
    bt1 = MFMA32(Y1.hi, Bhi, bt1); bt1 = MFMA32(Y1.hi, Blo, bt1); bt1 = MFMA32(Y1.lo, Bhi, bt1);
    float* Brow = Bo + (16 * T + li) * 28;
    *reinterpret_cast<float4*>(Brow + 4 * gl) = float4{bt0[0], bt0[1], bt0[2], bt0[3]};
    if (gl < 3)
      *reinterpret_cast<float4*>(Brow + 16 + 4 * gl) = float4{bt1[0], bt1[1], bt1[2], bt1[3]};
  }
}

extern "C" void kernel_launch(void* const* d_in, const int* in_sizes, int n_in,
                              void* d_out, int out_size, void* d_ws, size_t ws_size,
                              hipStream_t stream) {
  const float* x = (const float*)d_in[0];
  const float* W = (const float*)d_in[1];
  const float* b = (const float*)d_in[2];
  const int N = in_sizes[0] / 784;               // 4096 samples
  float* Xout = (float*)d_out;                   // [N,1,28,28]
  float* Bout = Xout + (size_t)N * 784;          // [N,1,512,28]
  uint4* wf = (uint4*)d_ws;                      // 65536 B
  prep_wfrag<<<8, 256, 0, stream>>>(W, wf);
  elm_kernel<<<N / 4, 256, 0, stream>>>(x, wf, b, Xout, Bout);
}